// Round 3
// baseline (418.359 us; speedup 1.0000x reference)
//
#include <hip/hip_runtime.h>
#include <hip/hip_bf16.h>
#include <hip/hip_cooperative_groups.h>

namespace cg = cooperative_groups;

#define NSAMP 128
#define AGENTS 64
#define D 128
#define NN (NSAMP * AGENTS)      // 8192
#define LOG2E 1.44269504088896340736f
#define LN2   0.69314718055994530942f
#define EPSF  1e-5f

typedef __attribute__((ext_vector_type(8))) short short8;
typedef __attribute__((ext_vector_type(4))) float floatx4;

__device__ __forceinline__ float u2f(unsigned v) {
    float f; __builtin_memcpy(&f, &v, 4); return f;
}
__device__ __forceinline__ unsigned f2u(float f) {
    unsigned v; __builtin_memcpy(&v, &f, 4); return v;
}
__device__ __forceinline__ unsigned short f2bf(float f) {
    unsigned x; __builtin_memcpy(&x, &f, 4);
    return (unsigned short)((x + 0x7FFFu + ((x >> 16) & 1u)) >> 16);
}

// MFMA 4-array gate pass for one layer (verified layouts):
//   A[m=lane&15][k=quad*8+j]; B[k][n] from WT[n][k]; C/D col=lane&15, row=quad*4+r.
__device__ __forceinline__ void mfma_gates(
    const short8 (&a)[4], const unsigned short* __restrict__ wl,
    const float* __restrict__ Wfp, const float* __restrict__ bfp,
    const float* __restrict__ Wsp, const float* __restrict__ bsp,
    const float* __restrict__ centers,
    int nbase, int w, int quad, int l16, int col,
    unsigned int (*EApk)[17], unsigned int (*EBpk)[17])
{
    floatx4 acc[4];
    #pragma unroll
    for (int arr = 0; arr < 4; ++arr) {
        const unsigned short* wp = wl + ((size_t)arr * 128 + col) * 128 + quad * 8;
        floatx4 ac = {0.f, 0.f, 0.f, 0.f};
        #pragma unroll
        for (int kc = 0; kc < 4; ++kc)
            ac = __builtin_amdgcn_mfma_f32_16x16x32_bf16(
                a[kc], *(const short8*)(wp + kc * 32), ac, 0, 0, 0);
        acc[arr] = ac;
    }
    const float cwf0 = Wfp[256 * D + col], cwf1 = Wfp[257 * D + col];
    const float cws0 = Wsp[256 * D + col], cws1 = Wsp[257 * D + col];
    const float bfv = bfp[col], bsv = bsp[col];
    #pragma unroll
    for (int r = 0; r < 4; ++r) {
        int row = w * 16 + quad * 4 + r;
        int n = nbase + row;
        float ce0 = centers[2 * n], ce1 = centers[2 * n + 1];
        float ctf = fmaf(ce0, cwf0, ce1 * cwf1);
        float cts = fmaf(ce0, cws0, ce1 * cws1);
        unsigned eaf = (unsigned)f2bf(__builtin_amdgcn_exp2f(-LOG2E * (acc[0][r] + ctf + bfv)));
        unsigned eas = (unsigned)f2bf(__builtin_amdgcn_exp2f( LOG2E * (acc[2][r] + cts + bsv)));
        unsigned ebf = (unsigned)f2bf(__builtin_amdgcn_exp2f(-LOG2E * (acc[1][r] - ctf)));
        unsigned ebs = (unsigned)f2bf(__builtin_amdgcn_exp2f( LOG2E * (acc[3][r] - cts)));
        EApk[row][l16] = eaf | (eas << 16);
        EBpk[row][l16] = ebf | (ebs << 16);
    }
}

// Edge aggregation over all 64 src rows for this thread's 4 dst rows x 1 col.
__device__ __forceinline__ void phaseB(
    const unsigned int (*EApk)[17], const unsigned int (*EBpk)[17],
    int cl, int slot, float (&v)[4], float& s1, float& s2)
{
    float eaf[4], eas[4], ac2[4];
    #pragma unroll
    for (int i = 0; i < 4; ++i) {
        unsigned pk = EApk[slot * 4 + i][cl];
        eaf[i] = u2f(pk << 16);
        eas[i] = u2f(pk & 0xFFFF0000u);
        ac2[i] = 0.f;
    }
    #pragma unroll 4
    for (int j = 0; j < 64; ++j) {
        unsigned pk = EBpk[j][cl];
        float ebf = u2f(pk << 16);
        float ebs = u2f(pk & 0xFFFF0000u);
        #pragma unroll
        for (int i = 0; i < 4; ++i) {
            float sg = __builtin_amdgcn_rcpf(fmaf(eaf[i], ebf, 1.f));
            float lg = __builtin_amdgcn_logf(fmaf(eas[i], ebs, 1.f));
            ac2[i] = fmaf(sg, lg, ac2[i]);
        }
    }
    s1 = 0.f; s2 = 0.f;
    #pragma unroll
    for (int i = 0; i < 4; ++i) {
        int dd = slot * 4 + i;
        unsigned pk = EBpk[dd][cl];
        float ebf = u2f(pk << 16);
        float ebs = u2f(pk & 0xFFFF0000u);
        float sg = __builtin_amdgcn_rcpf(fmaf(eaf[i], ebf, 1.f));
        float lg = __builtin_amdgcn_logf(fmaf(eas[i], ebs, 1.f));
        v[i] = (ac2[i] - sg * lg) * LN2;   // exact self-cancel (same inputs)
        s1 += v[i]; s2 += v[i] * v[i];
    }
}

// Per-block slot-tree reduce of (s1,s2), then one atomicAdd per (stat, col).
__device__ __forceinline__ void stats_tree(
    unsigned int (*EApk)[17], unsigned int (*EBpk)[17],
    int cl, int slot, int c, float s1, float s2, float* __restrict__ sc)
{
    __syncthreads();
    EApk[slot][cl] = f2u(s1);
    EBpk[slot][cl] = f2u(s2);
    __syncthreads();
    #pragma unroll
    for (int off = 8; off >= 1; off >>= 1) {
        if (slot < off) {
            EApk[slot][cl] = f2u(u2f(EApk[slot][cl]) + u2f(EApk[slot + off][cl]));
            EBpk[slot][cl] = f2u(u2f(EBpk[slot][cl]) + u2f(EBpk[slot + off][cl]));
        }
        __syncthreads();
    }
    if (slot == 0) {
        atomicAdd(&sc[c],       u2f(EApk[0][cl]));
        atomicAdd(&sc[128 + c], u2f(EBpk[0][cl]));
    }
}

// ---------------------------------------------------------------------------
// Persistent cooperative kernel (grid-strided tiles; works for ANY grid that
// is a multiple of 8, >= 8):
//   phase0 cvt+zero -> sync -> L1 tiles -> sync -> L2 tiles (BN1 folded,
//   x1 on the fly) -> sync -> elementwise BN2+res+relu.
// ---------------------------------------------------------------------------
__global__ __launch_bounds__(256, 4) void fused_gnn(
    const float* __restrict__ x0, const float* __restrict__ centers,
    const float* __restrict__ Wf1, const float* __restrict__ bf1,
    const float* __restrict__ Ws1, const float* __restrict__ bs1,
    const float* __restrict__ gm1, const float* __restrict__ bt1,
    const float* __restrict__ Wf2, const float* __restrict__ bf2,
    const float* __restrict__ Ws2, const float* __restrict__ bs2,
    const float* __restrict__ gm2, const float* __restrict__ bt2,
    unsigned short* __restrict__ WT, float* __restrict__ agg1,
    float* __restrict__ agg2, float* __restrict__ sacc,
    float* __restrict__ outp)
{
    cg::grid_group grid = cg::this_grid();
    const int tid = threadIdx.x, w = tid >> 6, lane = tid & 63;
    const int quad = lane >> 4, l16 = lane & 15;
    const int cl = tid & 15, slot = tid >> 4;
    const int q = blockIdx.x & 7;
    const int s0 = blockIdx.x >> 3;
    const int sStep = gridDim.x >> 3;
    const int c = q * 16 + cl;
    const int col = q * 16 + l16;

    __shared__ unsigned int EApk[64][17];
    __shared__ unsigned int EBpk[64][17];
    __shared__ float bnA[128], bnB[128];
    __shared__ float bn2A[128], bn2B[128];

    // ---- phase 0: weight transpose-convert + sacc zero (grid-strided) ----
    for (int job = blockIdx.x; job < 65; job += gridDim.x) {
        if (job < 64) {
            int rr = job * 16 + (tid >> 4);   // layer*512 + arr*128 + wc
            int kk = (tid & 15) * 8;
            int layer = rr >> 9, rem = rr & 511, arr = rem >> 7, wc = rem & 127;
            const float* M = (arr < 2) ? (layer ? Wf2 : Wf1) : (layer ? Ws2 : Ws1);
            int side = arr & 1;
            short8 sv;
            #pragma unroll
            for (int j = 0; j < 8; ++j)
                sv[j] = (short)f2bf(M[(size_t)(side * 128 + kk + j) * D + wc]);
            *(short8*)&WT[(size_t)(layer * 4 + arr) * 16384 + wc * 128 + kk] = sv;
        } else {
            sacc[tid] = 0.f;
            sacc[256 + tid] = 0.f;
        }
    }
    __builtin_amdgcn_fence(__ATOMIC_RELEASE, "agent");
    grid.sync();
    __builtin_amdgcn_fence(__ATOMIC_ACQUIRE, "agent");

    // ================= Layer 1 (tile loop) =================
    {
        float s1T = 0.f, s2T = 0.f;
        for (int s = s0; s < NSAMP; s += sStep) {
            const int nbase = s * AGENTS;
            short8 a[4];
            const float* xr = x0 + (size_t)(nbase + w * 16 + l16) * D + quad * 8;
            #pragma unroll
            for (int kc = 0; kc < 4; ++kc) {
                float4 v0 = *(const float4*)(xr + kc * 32);
                float4 v1 = *(const float4*)(xr + kc * 32 + 4);
                short8 t;
                t[0] = (short)f2bf(v0.x); t[1] = (short)f2bf(v0.y);
                t[2] = (short)f2bf(v0.z); t[3] = (short)f2bf(v0.w);
                t[4] = (short)f2bf(v1.x); t[5] = (short)f2bf(v1.y);
                t[6] = (short)f2bf(v1.z); t[7] = (short)f2bf(v1.w);
                a[kc] = t;
            }
            mfma_gates(a, WT, Wf1, bf1, Ws1, bs1, centers, nbase, w, quad, l16,
                       col, EApk, EBpk);
            __syncthreads();
            float v1a[4], s1, s2;
            phaseB(EApk, EBpk, cl, slot, v1a, s1, s2);
            #pragma unroll
            for (int i = 0; i < 4; ++i)
                agg1[(size_t)(nbase + slot * 4 + i) * D + c] = v1a[i];
            s1T += s1; s2T += s2;
            __syncthreads();          // gate reads done before next tile writes
        }
        stats_tree(EApk, EBpk, cl, slot, c, s1T, s2T, sacc);
    }
    __builtin_amdgcn_fence(__ATOMIC_RELEASE, "agent");
    grid.sync();
    __builtin_amdgcn_fence(__ATOMIC_ACQUIRE, "agent");

    // ================= Layer 2 (BN1 folded; x1 on the fly) =================
    if (tid < 128) {
        const float inv = 1.f / NN;
        float mu = sacc[tid] * inv;
        float var = sacc[128 + tid] * inv - mu * mu;
        float rs = rsqrtf(var + EPSF);
        float A = rs * gm1[tid];
        bnA[tid] = A;
        bnB[tid] = fmaf(-mu, A, bt1[tid]);
    }
    __syncthreads();
    {
        float s1T = 0.f, s2T = 0.f;
        for (int s = s0; s < NSAMP; s += sStep) {
            const int nbase = s * AGENTS;
            short8 a[4];
            const size_t ro = (size_t)(nbase + w * 16 + l16) * D + quad * 8;
            #pragma unroll
            for (int kc = 0; kc < 4; ++kc) {
                int cc = quad * 8 + kc * 32;
                float4 g0 = *(const float4*)&agg1[ro + kc * 32];
                float4 g1 = *(const float4*)&agg1[ro + kc * 32 + 4];
                float4 x0v = *(const float4*)(x0 + ro + kc * 32);
                float4 x1v = *(const float4*)(x0 + ro + kc * 32 + 4);
                float4 A0 = *(const float4*)&bnA[cc], A1 = *(const float4*)&bnA[cc + 4];
                float4 B0 = *(const float4*)&bnB[cc], B1 = *(const float4*)&bnB[cc + 4];
                short8 t;
                t[0] = (short)f2bf(fmaxf(0.f, fmaf(g0.x, A0.x, B0.x) + x0v.x));
                t[1] = (short)f2bf(fmaxf(0.f, fmaf(g0.y, A0.y, B0.y) + x0v.y));
                t[2] = (short)f2bf(fmaxf(0.f, fmaf(g0.z, A0.z, B0.z) + x0v.z));
                t[3] = (short)f2bf(fmaxf(0.f, fmaf(g0.w, A0.w, B0.w) + x0v.w));
                t[4] = (short)f2bf(fmaxf(0.f, fmaf(g1.x, A1.x, B1.x) + x1v.x));
                t[5] = (short)f2bf(fmaxf(0.f, fmaf(g1.y, A1.y, B1.y) + x1v.y));
                t[6] = (short)f2bf(fmaxf(0.f, fmaf(g1.z, A1.z, B1.z) + x1v.z));
                t[7] = (short)f2bf(fmaxf(0.f, fmaf(g1.w, A1.w, B1.w) + x1v.w));
                a[kc] = t;
            }
            mfma_gates(a, WT + 65536, Wf2, bf2, Ws2, bs2, centers, nbase, w,
                       quad, l16, col, EApk, EBpk);
            __syncthreads();
            float v2a[4], s1, s2;
            phaseB(EApk, EBpk, cl, slot, v2a, s1, s2);
            #pragma unroll
            for (int i = 0; i < 4; ++i)
                agg2[(size_t)(nbase + slot * 4 + i) * D + c] = v2a[i];
            s1T += s1; s2T += s2;
            __syncthreads();
        }
        stats_tree(EApk, EBpk, cl, slot, c, s1T, s2T, sacc + 256);
    }
    __builtin_amdgcn_fence(__ATOMIC_RELEASE, "agent");
    grid.sync();
    __builtin_amdgcn_fence(__ATOMIC_ACQUIRE, "agent");

    // ================= Final: BN2 + residual + relu (grid-strided) =========
    if (tid < 128) {
        const float inv = 1.f / NN;
        float mu = sacc[256 + tid] * inv;
        float var = sacc[384 + tid] * inv - mu * mu;
        float rs = rsqrtf(var + EPSF);
        float A = rs * gm2[tid];
        bn2A[tid] = A;
        bn2B[tid] = fmaf(-mu, A, bt2[tid]);
    }
    __syncthreads();
    for (int t = blockIdx.x * 256 + tid; t < NN * 16; t += gridDim.x * 256) {
        int n = t >> 4, c8 = (t & 15) * 8;
        size_t off = (size_t)n * D + c8;
        float o[8];
        #pragma unroll
        for (int h = 0; h < 2; ++h) {
            float4 g2 = *(const float4*)&agg2[off + h * 4];
            float4 g1 = *(const float4*)&agg1[off + h * 4];
            float4 xv = *(const float4*)&x0[off + h * 4];
            int cc = c8 + h * 4;
            o[h*4+0] = fmaxf(0.f, fmaf(g2.x, bn2A[cc+0], bn2B[cc+0]) +
                       fmaxf(0.f, fmaf(g1.x, bnA[cc+0], bnB[cc+0]) + xv.x));
            o[h*4+1] = fmaxf(0.f, fmaf(g2.y, bn2A[cc+1], bn2B[cc+1]) +
                       fmaxf(0.f, fmaf(g1.y, bnA[cc+1], bnB[cc+1]) + xv.y));
            o[h*4+2] = fmaxf(0.f, fmaf(g2.z, bn2A[cc+2], bn2B[cc+2]) +
                       fmaxf(0.f, fmaf(g1.z, bnA[cc+2], bnB[cc+2]) + xv.z));
            o[h*4+3] = fmaxf(0.f, fmaf(g2.w, bn2A[cc+3], bn2B[cc+3]) +
                       fmaxf(0.f, fmaf(g1.w, bnA[cc+3], bnB[cc+3]) + xv.w));
        }
        *(float4*)&outp[off]     = *(float4*)&o[0];
        *(float4*)&outp[off + 4] = *(float4*)&o[4];
    }
}

// ===========================================================================
// Fallback path: the verified 5-kernel pipeline (round-0, 148 us).
// ===========================================================================
__global__ __launch_bounds__(256) void cvt_kernel(
    const float* __restrict__ Wf1, const float* __restrict__ Ws1,
    const float* __restrict__ Wf2, const float* __restrict__ Ws2,
    unsigned short* __restrict__ WT, float* __restrict__ sacc)
{
    int b = blockIdx.x;
    if (b < 64) {
        int rr = b * 16 + (threadIdx.x >> 4);
        int kk = (threadIdx.x & 15) * 8;
        int layer = rr >> 9, rem = rr & 511, arr = rem >> 7, c = rem & 127;
        const float* M = (arr < 2) ? (layer ? Wf2 : Wf1) : (layer ? Ws2 : Ws1);
        int side = arr & 1;
        short8 s;
        #pragma unroll
        for (int j = 0; j < 8; ++j)
            s[j] = (short)f2bf(M[(size_t)(side * 128 + kk + j) * D + c]);
        *(short8*)&WT[(size_t)(layer * 4 + arr) * 16384 + c * 128 + kk] = s;
    } else {
        sacc[threadIdx.x]       = 0.f;
        sacc[256 + threadIdx.x] = 0.f;
    }
}

__global__ __launch_bounds__(256, 4) void prep_edge(
    const float* __restrict__ xin, const unsigned short* __restrict__ WT,
    const float* __restrict__ centers,
    const float* __restrict__ Wf, const float* __restrict__ bf_,
    const float* __restrict__ Ws, const float* __restrict__ bs_,
    float* __restrict__ agg, float* __restrict__ sacc)
{
    const int s = blockIdx.x >> 3, q = blockIdx.x & 7;
    const int nbase = s * AGENTS;
    const int tid = threadIdx.x, w = tid >> 6, lane = tid & 63;
    const int quad = lane >> 4, l16 = lane & 15;
    __shared__ unsigned int EApk[64][17];
    __shared__ unsigned int EBpk[64][17];
    const int col = q * 16 + l16;
    short8 a[4];
    {
        const float* xr = xin + (size_t)(nbase + w * 16 + l16) * D + quad * 8;
        #pragma unroll
        for (int kc = 0; kc < 4; ++kc) {
            float4 v0 = *(const float4*)(xr + kc * 32);
            float4 v1 = *(const float4*)(xr + kc * 32 + 4);
            short8 t;
            t[0] = (short)f2bf(v0.x); t[1] = (short)f2bf(v0.y);
            t[2] = (short)f2bf(v0.z); t[3] = (short)f2bf(v0.w);
            t[4] = (short)f2bf(v1.x); t[5] = (short)f2bf(v1.y);
            t[6] = (short)f2bf(v1.z); t[7] = (short)f2bf(v1.w);
            a[kc] = t;
        }
    }
    mfma_gates(a, WT, Wf, bf_, Ws, bs_, centers, nbase, w, quad, l16, col,
               EApk, EBpk);
    __syncthreads();
    const int cl = tid & 15, slot = tid >> 4;
    const int c = q * 16 + cl;
    float v[4], s1, s2;
    phaseB(EApk, EBpk, cl, slot, v, s1, s2);
    #pragma unroll
    for (int i = 0; i < 4; ++i)
        agg[(size_t)(nbase + slot * 4 + i) * D + c] = v[i];
    stats_tree(EApk, EBpk, cl, slot, c, s1, s2, sacc);
}

__global__ __launch_bounds__(256) void bn_kernel(
    const float* __restrict__ agg, const float* __restrict__ xin,
    const float* __restrict__ sacc,
    const float* __restrict__ gamma, const float* __restrict__ beta,
    float* __restrict__ outp)
{
    const int t = blockIdx.x * 256 + threadIdx.x;
    const int n = t >> 4;
    const int c = (t & 15) * 8;
    size_t off = (size_t)n * D + c;
    const float inv = 1.f / NN;
    float v[8];
    #pragma unroll
    for (int h = 0; h < 2; ++h) {
        float4 a  = *(const float4*)&agg[off + h * 4];
        float4 xv = *(const float4*)&xin[off + h * 4];
        float4 s1 = *(const float4*)&sacc[c + h * 4];
        float4 s2 = *(const float4*)&sacc[128 + c + h * 4];
        float4 gm = *(const float4*)&gamma[c + h * 4];
        float4 bt = *(const float4*)&beta[c + h * 4];
        float mu, var, rs;
        mu = s1.x * inv; var = s2.x * inv - mu * mu; rs = rsqrtf(var + EPSF);
        v[h*4+0] = fmaxf(0.f, fmaf((a.x - mu) * rs, gm.x, bt.x) + xv.x);
        mu = s1.y * inv; var = s2.y * inv - mu * mu; rs = rsqrtf(var + EPSF);
        v[h*4+1] = fmaxf(0.f, fmaf((a.y - mu) * rs, gm.y, bt.y) + xv.y);
        mu = s1.z * inv; var = s2.z * inv - mu * mu; rs = rsqrtf(var + EPSF);
        v[h*4+2] = fmaxf(0.f, fmaf((a.z - mu) * rs, gm.z, bt.z) + xv.z);
        mu = s1.w * inv; var = s2.w * inv - mu * mu; rs = rsqrtf(var + EPSF);
        v[h*4+3] = fmaxf(0.f, fmaf((a.w - mu) * rs, gm.w, bt.w) + xv.w);
    }
    *(float4*)&outp[off]     = *(float4*)&v[0];
    *(float4*)&outp[off + 4] = *(float4*)&v[4];
}

// ---------------------------------------------------------------------------
extern "C" void kernel_launch(void* const* d_in, const int* in_sizes, int n_in,
                              void* d_out, int out_size, void* d_ws, size_t ws_size,
                              hipStream_t stream) {
    const float* x0      = (const float*)d_in[0];
    const float* centers = (const float*)d_in[1];
    const float* Wf1 = (const float*)d_in[4];
    const float* bf1 = (const float*)d_in[5];
    const float* Ws1 = (const float*)d_in[6];
    const float* bs1 = (const float*)d_in[7];
    const float* gm1 = (const float*)d_in[8];
    const float* bt1 = (const float*)d_in[9];
    const float* Wf2 = (const float*)d_in[10];
    const float* bf2 = (const float*)d_in[11];
    const float* Ws2 = (const float*)d_in[12];
    const float* bs2 = (const float*)d_in[13];
    const float* gm2 = (const float*)d_in[14];
    const float* bt2 = (const float*)d_in[15];

    const size_t ND = (size_t)NN * D;              // 1048576
    unsigned short* WT = (unsigned short*)d_ws;    // 2 x 65536 bf16
    float* fbase = (float*)(WT + 2 * 65536);
    float* agg1  = fbase;                          // ND
    float* agg2  = fbase + ND;                     // ND (x1 in fallback)
    float* sacc  = fbase + 2 * ND;                 // 2 layers x 256
    float* outp  = (float*)d_out;

    // Size cooperative grid from the runtime's own occupancy query.
    static int coopGrid = -2;                      // -2 uncomputed, -1 disabled
    if (coopGrid == -2) {
        int occ = 0, cus = 0, dev = 0;
        hipError_t e1 = hipOccupancyMaxActiveBlocksPerMultiprocessor(
            &occ, (const void*)fused_gnn, 256, 0);
        (void)hipGetDevice(&dev);
        hipError_t e2 = hipDeviceGetAttribute(
            &cus, hipDeviceAttributeMultiprocessorCount, dev);
        if (e1 == hipSuccess && e2 == hipSuccess && occ > 0 && cus > 0) {
            long g = (long)occ * (long)cus;
            if (g > 1024) g = 1024;
            g -= (g & 7);                          // multiple of 8
            coopGrid = (g >= 8) ? (int)g : -1;
        } else {
            coopGrid = -1;
        }
        (void)hipGetLastError();                   // clear any sticky error
    }

    bool done = false;
    if (coopGrid > 0) {
        void* args[] = {
            (void*)&x0, (void*)&centers,
            (void*)&Wf1, (void*)&bf1, (void*)&Ws1, (void*)&bs1, (void*)&gm1, (void*)&bt1,
            (void*)&Wf2, (void*)&bf2, (void*)&Ws2, (void*)&bs2, (void*)&gm2, (void*)&bt2,
            (void*)&WT, (void*)&agg1, (void*)&agg2, (void*)&sacc, (void*)&outp
        };
        hipError_t e = hipLaunchCooperativeKernel(
            (const void*)fused_gnn, dim3(coopGrid), dim3(256), args, 0, stream);
        if (e == hipSuccess) {
            done = true;
        } else {
            (void)hipGetLastError();               // clear; use fallback forever
            coopGrid = -1;
        }
    }

    if (!done) {
        // Verified 5-kernel pipeline (agg2 doubles as x1 buffer).
        float* x1 = agg2;
        cvt_kernel<<<dim3(65), dim3(256), 0, stream>>>(
            Wf1, Ws1, Wf2, Ws2, WT, sacc);
        prep_edge<<<dim3(1024), dim3(256), 0, stream>>>(
            x0, WT, centers, Wf1, bf1, Ws1, bs1, agg1, sacc);
        bn_kernel<<<dim3(512), dim3(256), 0, stream>>>(
            agg1, x0, sacc, gm1, bt1, x1);
        prep_edge<<<dim3(1024), dim3(256), 0, stream>>>(
            x1, WT + 65536, centers, Wf2, bf2, Ws2, bs2, agg1, sacc + 256);
        bn_kernel<<<dim3(512), dim3(256), 0, stream>>>(
            agg1, x1, sacc + 256, gm2, bt2, outp);
    }
}

// Round 4
// 163.357 us; speedup vs baseline: 2.5610x; 2.5610x over previous
//
#include <hip/hip_runtime.h>
#include <hip/hip_bf16.h>

#define NSAMP 128
#define AGENTS 64
#define D 128
#define NN (NSAMP * AGENTS)      // 8192
#define LOG2E 1.44269504088896340736f
#define LN2   0.69314718055994530942f
#define EPSF  1e-5f

typedef __attribute__((ext_vector_type(8))) short short8;
typedef __attribute__((ext_vector_type(4))) float floatx4;

__device__ __forceinline__ float u2f(unsigned v) {
    float f; __builtin_memcpy(&f, &v, 4); return f;
}
__device__ __forceinline__ unsigned f2u(float f) {
    unsigned v; __builtin_memcpy(&v, &f, 4); return v;
}
__device__ __forceinline__ unsigned short f2bf(float f) {
    unsigned x; __builtin_memcpy(&x, &f, 4);
    return (unsigned short)((x + 0x7FFFu + ((x >> 16) & 1u)) >> 16);
}

// ---------------------------------------------------------------------------
// K0: build transposed bf16 weights WT[layer][arr][c][k] = Wside[k][c];
//     arr: 0=Af(dst) 1=Bf(src) 2=As(dst) 3=Bs(src).  Zero sacc (both layers).
// grid 65: 0..63 weights, 64 zeros sacc.  (verbatim from 148us baseline)
// ---------------------------------------------------------------------------
__global__ __launch_bounds__(256) void cvt_kernel(
    const float* __restrict__ Wf1, const float* __restrict__ Ws1,
    const float* __restrict__ Wf2, const float* __restrict__ Ws2,
    unsigned short* __restrict__ WT, float* __restrict__ sacc)
{
    int b = blockIdx.x;
    if (b < 64) {
        int rr = b * 16 + (threadIdx.x >> 4);   // layer*512 + arr*128 + c
        int kk = (threadIdx.x & 15) * 8;
        int layer = rr >> 9, rem = rr & 511, arr = rem >> 7, c = rem & 127;
        const float* M = (arr < 2) ? (layer ? Wf2 : Wf1) : (layer ? Ws2 : Ws1);
        int side = arr & 1;
        short8 s;
        #pragma unroll
        for (int j = 0; j < 8; ++j)
            s[j] = (short)f2bf(M[(size_t)(side * 128 + kk + j) * D + c]);
        *(short8*)&WT[(size_t)(layer * 4 + arr) * 16384 + c * 128 + kk] = s;
    } else {
        sacc[threadIdx.x]       = 0.f;
        sacc[256 + threadIdx.x] = 0.f;
    }
}

// Per-block slot-tree reduce of (s1,s2), then one atomicAdd per (stat, col).
__device__ __forceinline__ void stats_tree(
    unsigned int (*EApk)[17], unsigned int (*EBpk)[17],
    int cl, int slot, int c, float s1, float s2, float* __restrict__ sc)
{
    __syncthreads();                         // all gate reads done; reuse LDS
    EApk[slot][cl] = f2u(s1);
    EBpk[slot][cl] = f2u(s2);
    __syncthreads();
    #pragma unroll
    for (int off = 8; off >= 1; off >>= 1) {
        if (slot < off) {
            EApk[slot][cl] = f2u(u2f(EApk[slot][cl]) + u2f(EApk[slot + off][cl]));
            EBpk[slot][cl] = f2u(u2f(EBpk[slot][cl]) + u2f(EBpk[slot + off][cl]));
        }
        __syncthreads();
    }
    if (slot == 0) {
        atomicAdd(&sc[c],       u2f(EApk[0][cl]));
        atomicAdd(&sc[128 + c], u2f(EBpk[0][cl]));
    }
}

// ---------------------------------------------------------------------------
// K1/K2: half-sample prep. Block = (s, q, h): EA gates for 32 dst rows
// (h half), EB gates for all 64 src rows; phaseB = 2 dst rows/thread.
// grid 2048 -> 8 blocks/CU (100% occupancy target).
// LAYER==2: BN1 folded, x1 computed on the fly from agg1+x0 (verified math).
// ---------------------------------------------------------------------------
template<int LAYER>
__global__ __launch_bounds__(256, 8) void prep_half(
    const float* __restrict__ xin,           // x0
    const float* __restrict__ agg_in,        // LAYER==2: agg1
    const unsigned short* __restrict__ WT,   // this layer's [4][128][128] bf16
    const float* __restrict__ centers,
    const float* __restrict__ Wf, const float* __restrict__ bf_,
    const float* __restrict__ Ws, const float* __restrict__ bs_,
    const float* __restrict__ gm_prev, const float* __restrict__ bt_prev,
    const float* __restrict__ sacc_prev,     // LAYER==2: layer-1 raw sums
    float* __restrict__ agg_out, float* __restrict__ sacc_out)
{
    const int bid = blockIdx.x;
    const int s = bid >> 4, q = (bid >> 1) & 7, h = bid & 1;
    const int nbase = s * AGENTS;
    const int tid = threadIdx.x, w = tid >> 6, lane = tid & 63;
    const int quad = lane >> 4, l16 = lane & 15;
    const int col = q * 16 + l16;

    __shared__ unsigned int EApk[32][17];    // local dst rows (h half)
    __shared__ unsigned int EBpk[64][17];    // all src rows
    __shared__ float bnA[128], bnB[128];     // LAYER==2 only

    if (LAYER == 2) {
        if (tid < 128) {
            const float inv = 1.f / NN;
            float mu = sacc_prev[tid] * inv;
            float var = sacc_prev[128 + tid] * inv - mu * mu;
            float rs = rsqrtf(var + EPSF);
            float A = rs * gm_prev[tid];
            bnA[tid] = A;
            bnB[tid] = fmaf(-mu, A, bt_prev[tid]);
        }
        __syncthreads();
    }

    // ---- Phase A: A-fragments for this wave's 16 rows ----
    short8 a[4];
    if (LAYER == 1) {
        const float* xr = xin + (size_t)(nbase + w * 16 + l16) * D + quad * 8;
        #pragma unroll
        for (int kc = 0; kc < 4; ++kc) {
            float4 v0 = *(const float4*)(xr + kc * 32);
            float4 v1 = *(const float4*)(xr + kc * 32 + 4);
            short8 t;
            t[0] = (short)f2bf(v0.x); t[1] = (short)f2bf(v0.y);
            t[2] = (short)f2bf(v0.z); t[3] = (short)f2bf(v0.w);
            t[4] = (short)f2bf(v1.x); t[5] = (short)f2bf(v1.y);
            t[6] = (short)f2bf(v1.z); t[7] = (short)f2bf(v1.w);
            a[kc] = t;
        }
    } else {
        // x1 on the fly: relu(agg1*A + B + x0)   (verified in coop run)
        const size_t ro = (size_t)(nbase + w * 16 + l16) * D + quad * 8;
        #pragma unroll
        for (int kc = 0; kc < 4; ++kc) {
            int cc = quad * 8 + kc * 32;
            float4 g0 = *(const float4*)&agg_in[ro + kc * 32];
            float4 g1 = *(const float4*)&agg_in[ro + kc * 32 + 4];
            float4 x0v = *(const float4*)(xin + ro + kc * 32);
            float4 x1v = *(const float4*)(xin + ro + kc * 32 + 4);
            float4 A0 = *(const float4*)&bnA[cc], A1 = *(const float4*)&bnA[cc + 4];
            float4 B0 = *(const float4*)&bnB[cc], B1 = *(const float4*)&bnB[cc + 4];
            short8 t;
            t[0] = (short)f2bf(fmaxf(0.f, fmaf(g0.x, A0.x, B0.x) + x0v.x));
            t[1] = (short)f2bf(fmaxf(0.f, fmaf(g0.y, A0.y, B0.y) + x0v.y));
            t[2] = (short)f2bf(fmaxf(0.f, fmaf(g0.z, A0.z, B0.z) + x0v.z));
            t[3] = (short)f2bf(fmaxf(0.f, fmaf(g0.w, A0.w, B0.w) + x0v.w));
            t[4] = (short)f2bf(fmaxf(0.f, fmaf(g1.x, A1.x, B1.x) + x1v.x));
            t[5] = (short)f2bf(fmaxf(0.f, fmaf(g1.y, A1.y, B1.y) + x1v.y));
            t[6] = (short)f2bf(fmaxf(0.f, fmaf(g1.z, A1.z, B1.z) + x1v.z));
            t[7] = (short)f2bf(fmaxf(0.f, fmaf(g1.w, A1.w, B1.w) + x1v.w));
            a[kc] = t;
        }
    }

    // ---- MFMA: EB (arrs 1,3) for all waves; EA (arrs 0,2) if dst half ----
    const int doEA = ((w >> 1) == h);
    floatx4 accB[2];
    #pragma unroll
    for (int a2 = 0; a2 < 2; ++a2) {
        const int arr = 1 + 2 * a2;
        const unsigned short* wp = WT + ((size_t)arr * 128 + col) * 128 + quad * 8;
        floatx4 ac = {0.f, 0.f, 0.f, 0.f};
        #pragma unroll
        for (int kc = 0; kc < 4; ++kc)
            ac = __builtin_amdgcn_mfma_f32_16x16x32_bf16(
                a[kc], *(const short8*)(wp + kc * 32), ac, 0, 0, 0);
        accB[a2] = ac;
    }
    floatx4 accA[2] = {{0,0,0,0},{0,0,0,0}};
    if (doEA) {
        #pragma unroll
        for (int a2 = 0; a2 < 2; ++a2) {
            const int arr = 2 * a2;
            const unsigned short* wp = WT + ((size_t)arr * 128 + col) * 128 + quad * 8;
            floatx4 ac = {0.f, 0.f, 0.f, 0.f};
            #pragma unroll
            for (int kc = 0; kc < 4; ++kc)
                ac = __builtin_amdgcn_mfma_f32_16x16x32_bf16(
                    a[kc], *(const short8*)(wp + kc * 32), ac, 0, 0, 0);
            accA[a2] = ac;
        }
    }
    const float cwf0 = Wf[256 * D + col], cwf1 = Wf[257 * D + col];
    const float cws0 = Ws[256 * D + col], cws1 = Ws[257 * D + col];
    const float bfv = bf_[col], bsv = bs_[col];
    #pragma unroll
    for (int r = 0; r < 4; ++r) {
        int row = w * 16 + quad * 4 + r;              // 0..63 src row
        int n = nbase + row;
        float ce0 = centers[2 * n], ce1 = centers[2 * n + 1];
        float ctf = fmaf(ce0, cwf0, ce1 * cwf1);
        float cts = fmaf(ce0, cws0, ce1 * cws1);
        unsigned ebf = (unsigned)f2bf(__builtin_amdgcn_exp2f(-LOG2E * (accB[0][r] - ctf)));
        unsigned ebs = (unsigned)f2bf(__builtin_amdgcn_exp2f( LOG2E * (accB[1][r] - cts)));
        EBpk[row][l16] = ebf | (ebs << 16);
        if (doEA) {
            unsigned eaf = (unsigned)f2bf(__builtin_amdgcn_exp2f(-LOG2E * (accA[0][r] + ctf + bfv)));
            unsigned eas = (unsigned)f2bf(__builtin_amdgcn_exp2f( LOG2E * (accA[1][r] + cts + bsv)));
            EApk[(w & 1) * 16 + quad * 4 + r][l16] = eaf | (eas << 16);
        }
    }
    __syncthreads();

    // ---- Phase B: 2 dst rows per thread over all 64 src rows ----
    const int cl = tid & 15, slot = tid >> 4;
    const int c = q * 16 + cl;
    float eaf[2], eas[2], ac2[2];
    #pragma unroll
    for (int i = 0; i < 2; ++i) {
        unsigned pk = EApk[slot * 2 + i][cl];
        eaf[i] = u2f(pk << 16);
        eas[i] = u2f(pk & 0xFFFF0000u);
        ac2[i] = 0.f;
    }
    #pragma unroll 8
    for (int j = 0; j < 64; ++j) {
        unsigned pk = EBpk[j][cl];
        float ebf = u2f(pk << 16);
        float ebs = u2f(pk & 0xFFFF0000u);
        #pragma unroll
        for (int i = 0; i < 2; ++i) {
            float sg = __builtin_amdgcn_rcpf(fmaf(eaf[i], ebf, 1.f));
            float lg = __builtin_amdgcn_logf(fmaf(eas[i], ebs, 1.f));
            ac2[i] = fmaf(sg, lg, ac2[i]);
        }
    }
    float s1 = 0.f, s2 = 0.f;
    #pragma unroll
    for (int i = 0; i < 2; ++i) {
        int d = h * 32 + slot * 2 + i;                // global dst row
        unsigned pk = EBpk[d][cl];
        float ebf = u2f(pk << 16);
        float ebs = u2f(pk & 0xFFFF0000u);
        float sg = __builtin_amdgcn_rcpf(fmaf(eaf[i], ebf, 1.f));
        float lg = __builtin_amdgcn_logf(fmaf(eas[i], ebs, 1.f));
        float v = (ac2[i] - sg * lg) * LN2;           // exact self-cancel
        agg_out[(size_t)(nbase + d) * D + c] = v;
        s1 += v; s2 += v * v;
    }
    stats_tree(EApk, EBpk, cl, slot, c, s1, s2, sacc_out);
}

// ---------------------------------------------------------------------------
// K3: final BN2 + residual (x1 recomputed from agg1) + relu -> out.
// grid 512 x 256, 8 elems/thread.  (verified math from coop run)
// ---------------------------------------------------------------------------
__global__ __launch_bounds__(256) void final_bn(
    const float* __restrict__ x0, const float* __restrict__ agg1,
    const float* __restrict__ agg2, const float* __restrict__ sacc,
    const float* __restrict__ gm1, const float* __restrict__ bt1,
    const float* __restrict__ gm2, const float* __restrict__ bt2,
    float* __restrict__ outp)
{
    const int tid = threadIdx.x;
    __shared__ float bnA[128], bnB[128], bn2A[128], bn2B[128];
    if (tid < 128) {
        const float inv = 1.f / NN;
        float mu = sacc[tid] * inv;
        float var = sacc[128 + tid] * inv - mu * mu;
        float rs = rsqrtf(var + EPSF);
        float A = rs * gm1[tid];
        bnA[tid] = A;
        bnB[tid] = fmaf(-mu, A, bt1[tid]);
        float mu2 = sacc[256 + tid] * inv;
        float var2 = sacc[384 + tid] * inv - mu2 * mu2;
        float rs2 = rsqrtf(var2 + EPSF);
        float A2 = rs2 * gm2[tid];
        bn2A[tid] = A2;
        bn2B[tid] = fmaf(-mu2, A2, bt2[tid]);
    }
    __syncthreads();
    const int t = blockIdx.x * 256 + tid;
    const int n = t >> 4, c8 = (t & 15) * 8;
    size_t off = (size_t)n * D + c8;
    float o[8];
    #pragma unroll
    for (int hh = 0; hh < 2; ++hh) {
        float4 g2 = *(const float4*)&agg2[off + hh * 4];
        float4 g1 = *(const float4*)&agg1[off + hh * 4];
        float4 xv = *(const float4*)&x0[off + hh * 4];
        int cc = c8 + hh * 4;
        o[hh*4+0] = fmaxf(0.f, fmaf(g2.x, bn2A[cc+0], bn2B[cc+0]) +
                    fmaxf(0.f, fmaf(g1.x, bnA[cc+0], bnB[cc+0]) + xv.x));
        o[hh*4+1] = fmaxf(0.f, fmaf(g2.y, bn2A[cc+1], bn2B[cc+1]) +
                    fmaxf(0.f, fmaf(g1.y, bnA[cc+1], bnB[cc+1]) + xv.y));
        o[hh*4+2] = fmaxf(0.f, fmaf(g2.z, bn2A[cc+2], bn2B[cc+2]) +
                    fmaxf(0.f, fmaf(g1.z, bnA[cc+2], bnB[cc+2]) + xv.z));
        o[hh*4+3] = fmaxf(0.f, fmaf(g2.w, bn2A[cc+3], bn2B[cc+3]) +
                    fmaxf(0.f, fmaf(g1.w, bnA[cc+3], bnB[cc+3]) + xv.w));
    }
    *(float4*)&outp[off]     = *(float4*)&o[0];
    *(float4*)&outp[off + 4] = *(float4*)&o[4];
}

// ---------------------------------------------------------------------------
extern "C" void kernel_launch(void* const* d_in, const int* in_sizes, int n_in,
                              void* d_out, int out_size, void* d_ws, size_t ws_size,
                              hipStream_t stream) {
    const float* x0      = (const float*)d_in[0];
    const float* centers = (const float*)d_in[1];
    // d_in[2], d_in[3]: edge lists — clique structure is deterministic, unused.
    const float* Wf1 = (const float*)d_in[4];
    const float* bf1 = (const float*)d_in[5];
    const float* Ws1 = (const float*)d_in[6];
    const float* bs1 = (const float*)d_in[7];
    const float* gm1 = (const float*)d_in[8];
    const float* bt1 = (const float*)d_in[9];
    const float* Wf2 = (const float*)d_in[10];
    const float* bf2 = (const float*)d_in[11];
    const float* Ws2 = (const float*)d_in[12];
    const float* bs2 = (const float*)d_in[13];
    const float* gm2 = (const float*)d_in[14];
    const float* bt2 = (const float*)d_in[15];

    const size_t ND = (size_t)NN * D;              // 1048576
    unsigned short* WT = (unsigned short*)d_ws;    // 2 x 65536 bf16
    float* fbase = (float*)(WT + 2 * 65536);
    float* agg1  = fbase;                          // ND
    float* agg2  = fbase + ND;                     // ND
    float* sacc  = fbase + 2 * ND;                 // 2 layers x 256
    float* outp  = (float*)d_out;

    cvt_kernel<<<dim3(65), dim3(256), 0, stream>>>(
        Wf1, Ws1, Wf2, Ws2, WT, sacc);

    prep_half<1><<<dim3(2048), dim3(256), 0, stream>>>(
        x0, agg1 /*unused*/, WT, centers, Wf1, bf1, Ws1, bs1,
        gm1 /*unused*/, bt1 /*unused*/, sacc /*unused*/, agg1, sacc);

    prep_half<2><<<dim3(2048), dim3(256), 0, stream>>>(
        x0, agg1, WT + 65536, centers, Wf2, bf2, Ws2, bs2,
        gm1, bt1, sacc, agg2, sacc + 256);

    final_bn<<<dim3(512), dim3(256), 0, stream>>>(
        x0, agg1, agg2, sacc, gm1, bt1, gm2, bt2, outp);
}